// Round 3
// baseline (551.492 us; speedup 1.0000x reference)
//
#include <hip/hip_runtime.h>
#include <hip/hip_cooperative_groups.h>
#include <cmath>

namespace cg = cooperative_groups;

#define NN 64
#define CC 256
#define TT 64
#define VV 25
#define OO 512     // 2*out_planes
#define GG 8
#define NV (NN*VV)   // 1600 elements per channel for qkv/so BN
#define STK 625      // V*V
#define NBLK 512
#define NTHR 256

union SMem {
    float gemm_ys[CC * VV];                  // 6400 floats = 25.6 KB (max member)
    struct {
        float qs[16][VV], ks[16][VV], rs[32][49];
        float qscl[32], qshl[32];
        float red[3][256];
    } sc;                                    // ~12.8 KB
    struct {
        float S[STK], vs[32][VV], rs[32][49], scratch[64 * VV];
        float sscl[3], sshl[3], vscl[32], vshl[32];
    } at;                                    // ~18.7 KB
    struct {
        float osl[64], oshl[64], orows[32][VV];
    } fin;                                   // 3.7 KB
};

__global__ __launch_bounds__(256, 2) void k_all(
    const float* __restrict__ x, const float* __restrict__ w,
    const float* __restrict__ rel,
    const float* __restrict__ gq, const float* __restrict__ bq,
    const float* __restrict__ gs, const float* __restrict__ bs,
    const float* __restrict__ go, const float* __restrict__ bo,
    float* __restrict__ y, float* __restrict__ qkv,
    float* __restrict__ stk, float* __restrict__ so,
    float* __restrict__ qstat, float* __restrict__ sstat, float* __restrict__ ostat,
    float* __restrict__ out)
{
    cg::grid_group grid = cg::this_grid();
    __shared__ SMem sm;
    const int t = threadIdx.x;
    const int b = blockIdx.x;

    // ================= phase 0: zero stat accumulators + y = mean_T(x) =================
    if (b == 0) {
        for (int i = t; i < 2096; i += NTHR) qstat[i] = 0.f;  // qstat,sstat,ostat contiguous
    }
    for (int o = b * NTHR + t; o < 16384 * VV; o += NBLK * NTHR) {
        int row = o / VV, v = o - VV * row;
        const float* xr = x + (size_t)row * (TT * VV) + v;
        float s = 0.f;
        #pragma unroll
        for (int tt = 0; tt < TT; ++tt) s += xr[tt * VV];
        y[o] = s * (1.0f / TT);
    }
    grid.sync();

    // ================= phase 1: qkv = w @ y, fused per-channel (sum,sumsq) =================
    {
        int n = b >> 3, oc = b & 7;
        const float* yp = y + (size_t)n * CC * VV;
        for (int i = t; i < CC * VV; i += NTHR) sm.gemm_ys[i] = yp[i];
        __syncthreads();
        int v = t % VV, o0 = t / VV;        // valid for t<200
        int obase = oc * 64 + o0;
        float acc[8] = {0, 0, 0, 0, 0, 0, 0, 0};
        if (t < 200) {
            for (int c = 0; c < CC; c += 4) {
                float y0 = sm.gemm_ys[c * VV + v],       y1 = sm.gemm_ys[(c + 1) * VV + v];
                float y2 = sm.gemm_ys[(c + 2) * VV + v], y3 = sm.gemm_ys[(c + 3) * VV + v];
                #pragma unroll
                for (int u = 0; u < 8; ++u) {
                    const float4 w4 = *(const float4*)&w[(size_t)(obase + u * 8) * CC + c];
                    acc[u] += y0 * w4.x + y1 * w4.y + y2 * w4.z + y3 * w4.w;
                }
            }
            #pragma unroll
            for (int u = 0; u < 8; ++u)
                qkv[((size_t)n * OO + obase + u * 8) * VV + v] = acc[u];
        }
        __syncthreads();                    // done reading ys -> reuse as scratch
        if (t < 200) {
            #pragma unroll
            for (int u = 0; u < 8; ++u) sm.gemm_ys[(o0 + 8 * u) * VV + v] = acc[u];
        }
        __syncthreads();
        if (t < 64) {
            float s = 0.f, s2 = 0.f;
            #pragma unroll
            for (int k2 = 0; k2 < VV; ++k2) { float w0 = sm.gemm_ys[t * VV + k2]; s += w0; s2 += w0 * w0; }
            int ch = oc * 64 + t;
            atomicAdd(&qstat[2 * ch], s);
            atomicAdd(&qstat[2 * ch + 1], s2);
        }
    }
    grid.sync();

    // ================= phase 2: qkv-BN -> qk/qr/kr scores, fused sim stats =================
    {
        int n = b >> 3, gidx = b & 7;
        if (t < 32) {
            int o = gidx * 64 + t;
            float s = qstat[2 * o], s2 = qstat[2 * o + 1];
            float m = s * (1.0f / NV), var = s2 * (1.0f / NV) - m * m;
            float sc = gq[o] * rsqrtf(var + 1e-5f);
            sm.sc.qscl[t] = sc; sm.sc.qshl[t] = bq[o] - m * sc;
        }
        __syncthreads();
        for (int i = t; i < 32 * VV; i += NTHR) {
            int c = i / VV, v = i - c * VV;
            int o = gidx * 64 + c;
            float val = qkv[((size_t)n * OO + o) * VV + v] * sm.sc.qscl[c] + sm.sc.qshl[c];
            if (c < 16) sm.sc.qs[c][v] = val; else sm.sc.ks[c - 16][v] = val;
        }
        for (int i = t; i < 32 * 49; i += NTHR) sm.sc.rs[i / 49][i % 49] = rel[i];
        __syncthreads();
        float sqk = 0.f, sqr = 0.f, skr = 0.f, sqk2 = 0.f, sqr2 = 0.f, skr2 = 0.f;
        for (int ij = t; ij < STK; ij += NTHR) {
            int i = ij / VV, j = ij - (ij / VV) * VV;
            float aqk = 0.f, aqr = 0.f, akr = 0.f;
            #pragma unroll
            for (int c = 0; c < 16; ++c) {
                float qv = sm.sc.qs[c][i], kv = sm.sc.ks[c][j];
                aqk += qv * kv;
                aqr += qv * sm.sc.rs[c][i - j + 24];
                akr += kv * sm.sc.rs[16 + c][j - i + 24];
            }
            size_t base = (size_t)n * 24;
            stk[(base + gidx) * STK + ij]      = aqk;
            stk[(base + 8 + gidx) * STK + ij]  = aqr;
            stk[(base + 16 + gidx) * STK + ij] = akr;
            sqk += aqk; sqk2 += aqk * aqk;
            sqr += aqr; sqr2 += aqr * aqr;
            skr += akr; skr2 += akr * akr;
        }
        sm.sc.red[0][t] = sqk; sm.sc.red[1][t] = sqr; sm.sc.red[2][t] = skr;
        __syncthreads();
        for (int off = 128; off > 0; off >>= 1) {
            if (t < off) {
                sm.sc.red[0][t] += sm.sc.red[0][t + off];
                sm.sc.red[1][t] += sm.sc.red[1][t + off];
                sm.sc.red[2][t] += sm.sc.red[2][t + off];
            }
            __syncthreads();
        }
        if (t == 0) {
            atomicAdd(&sstat[2 * gidx], sm.sc.red[0][0]);
            atomicAdd(&sstat[2 * (8 + gidx)], sm.sc.red[1][0]);
            atomicAdd(&sstat[2 * (16 + gidx)], sm.sc.red[2][0]);
        }
        __syncthreads();
        sm.sc.red[0][t] = sqk2; sm.sc.red[1][t] = sqr2; sm.sc.red[2][t] = skr2;
        __syncthreads();
        for (int off = 128; off > 0; off >>= 1) {
            if (t < off) {
                sm.sc.red[0][t] += sm.sc.red[0][t + off];
                sm.sc.red[1][t] += sm.sc.red[1][t + off];
                sm.sc.red[2][t] += sm.sc.red[2][t + off];
            }
            __syncthreads();
        }
        if (t == 0) {
            atomicAdd(&sstat[2 * gidx + 1], sm.sc.red[0][0]);
            atomicAdd(&sstat[2 * (8 + gidx) + 1], sm.sc.red[1][0]);
            atomicAdd(&sstat[2 * (16 + gidx) + 1], sm.sc.red[2][0]);
        }
    }
    grid.sync();

    // ================= phase 3: sim-BN+sum -> softmax -> sv/sve, fused so stats =================
    {
        int n = b >> 3, gidx = b & 7;
        if (t < 3) {
            int ch = 8 * t + gidx;
            float s = sstat[2 * ch], s2 = sstat[2 * ch + 1];
            const float inv = 1.0f / 40000.0f;
            float m = s * inv, var = s2 * inv - m * m;
            float sc = gs[ch] * rsqrtf(var + 1e-5f);
            sm.at.sscl[t] = sc; sm.at.sshl[t] = bs[ch] - m * sc;
        }
        if (t >= 32 && t < 64) {
            int c = t - 32;
            int o = gidx * 64 + 32 + c;
            float s = qstat[2 * o], s2 = qstat[2 * o + 1];
            float m = s * (1.0f / NV), var = s2 * (1.0f / NV) - m * m;
            float sc = gq[o] * rsqrtf(var + 1e-5f);
            sm.at.vscl[c] = sc; sm.at.vshl[c] = bq[o] - m * sc;
        }
        __syncthreads();
        const size_t sb = (size_t)n * 24 * STK;
        for (int ij = t; ij < STK; ij += NTHR) {
            float a = stk[sb + (size_t)gidx * STK + ij] * sm.at.sscl[0] + sm.at.sshl[0];
            a += stk[sb + (size_t)(8 + gidx) * STK + ij] * sm.at.sscl[1] + sm.at.sshl[1];
            a += stk[sb + (size_t)(16 + gidx) * STK + ij] * sm.at.sscl[2] + sm.at.sshl[2];
            sm.at.S[ij] = a;
        }
        for (int i = t; i < 32 * VV; i += NTHR) {
            int c = i / VV, v = i - (i / VV) * VV;
            int o = gidx * 64 + 32 + c;
            sm.at.vs[c][v] = qkv[((size_t)n * OO + o) * VV + v] * sm.at.vscl[c] + sm.at.vshl[c];
        }
        for (int i = t; i < 32 * 49; i += NTHR) sm.at.rs[i / 49][i % 49] = rel[32 * 49 + i];
        __syncthreads();
        if (t < VV) {
            int i = t;
            float m = -1e30f;
            #pragma unroll
            for (int j = 0; j < VV; ++j) m = fmaxf(m, sm.at.S[i * VV + j]);
            float sum = 0.f;
            float e[VV];
            #pragma unroll
            for (int j = 0; j < VV; ++j) { e[j] = expf(sm.at.S[i * VV + j] - m); sum += e[j]; }
            float inv = 1.0f / sum;
            #pragma unroll
            for (int j = 0; j < VV; ++j) sm.at.S[i * VV + j] = e[j] * inv;
        }
        __syncthreads();
        for (int idx = t; idx < 32 * VV; idx += NTHR) {
            int c = idx / VV, i = idx - (idx / VV) * VV;
            float sv = 0.f, sve = 0.f;
            #pragma unroll
            for (int j = 0; j < VV; ++j) {
                float p = sm.at.S[i * VV + j];
                sv  += p * sm.at.vs[c][j];
                sve += p * sm.at.rs[c][i - j + 24];
            }
            size_t o = (size_t)(gidx * 32 + c) * 2;
            so[((size_t)n * OO + o) * VV + i]     = sv;
            so[((size_t)n * OO + o + 1) * VV + i] = sve;
            sm.at.scratch[(2 * c) * VV + i]     = sv;
            sm.at.scratch[(2 * c + 1) * VV + i] = sve;
        }
        __syncthreads();
        if (t < 64) {
            float s = 0.f, s2 = 0.f;
            #pragma unroll
            for (int k2 = 0; k2 < VV; ++k2) { float w0 = sm.at.scratch[t * VV + k2]; s += w0; s2 += w0 * w0; }
            int ch = gidx * 64 + t;
            atomicAdd(&ostat[2 * ch], s);
            atomicAdd(&ostat[2 * ch + 1], s2);
        }
    }
    grid.sync();

    // ================= phase 4: out = x * (1 + sigmoid(bn(so0)+bn(so1))) =================
    {
        int row0 = b * 32;                 // 32 consecutive (n,p) rows, same n
        int n = row0 >> 8;
        int p0 = row0 & 255;
        if (t < 64) {
            int r = t >> 1, half = t & 1;
            int ch = 2 * (p0 + r) + half;
            float s = ostat[2 * ch], s2 = ostat[2 * ch + 1];
            float m = s * (1.0f / NV), var = s2 * (1.0f / NV) - m * m;
            float scv = go[ch] * rsqrtf(var + 1e-5f);
            sm.fin.osl[t] = scv; sm.fin.oshl[t] = bo[ch] - m * scv;
        }
        __syncthreads();
        for (int i = t; i < 32 * VV; i += NTHR) {
            int r = i / VV, v = i - VV * r;
            int p = p0 + r;
            const float* sop = so + ((size_t)n * OO + 2 * p) * VV + v;
            float a  = sop[0]  * sm.fin.osl[2 * r]     + sm.fin.oshl[2 * r];
            float b2 = sop[VV] * sm.fin.osl[2 * r + 1] + sm.fin.oshl[2 * r + 1];
            float z = a + b2;
            sm.fin.orows[r][v] = 1.0f + 1.0f / (1.0f + expf(-z));
        }
        __syncthreads();
        const float4* x4 = (const float4*)(x + (size_t)row0 * (TT * VV));
        float4* o4 = (float4*)(out + (size_t)row0 * (TT * VV));
        for (int i = t; i < 32 * 400; i += NTHR) {
            int r = i / 400; int e = (i - 400 * r) * 4; int v0 = e % VV;
            float4 xv = x4[i]; float4 rr;
            int v;
            v = v0;                       rr.x = xv.x * sm.fin.orows[r][v];
            v = v0 + 1; if (v >= VV) v -= VV; rr.y = xv.y * sm.fin.orows[r][v];
            v = v0 + 2; if (v >= VV) v -= VV; rr.z = xv.z * sm.fin.orows[r][v];
            v = v0 + 3; if (v >= VV) v -= VV; rr.w = xv.w * sm.fin.orows[r][v];
            o4[i] = rr;
        }
    }
}

extern "C" void kernel_launch(void* const* d_in, const int* in_sizes, int n_in,
                              void* d_out, int out_size, void* d_ws, size_t ws_size,
                              hipStream_t stream) {
    (void)in_sizes; (void)n_in; (void)out_size; (void)ws_size;
    const float* x        = (const float*)d_in[0];
    const float* w_qkv    = (const float*)d_in[1];
    const float* relative = (const float*)d_in[2];
    const float* bn_qkv_g = (const float*)d_in[3];
    const float* bn_qkv_b = (const float*)d_in[4];
    const float* bn_sim_g = (const float*)d_in[5];
    const float* bn_sim_b = (const float*)d_in[6];
    const float* bn_out_g = (const float*)d_in[7];
    const float* bn_out_b = (const float*)d_in[8];
    float* out = (float*)d_out;

    float* ws = (float*)d_ws;
    float* w_y    = ws;                 // NN*CC*VV      = 409600
    float* w_qkvp = ws + 409600;        // NN*OO*VV      = 819200
    float* w_stk  = ws + 1228800;       // NN*24*STK     = 960000
    float* w_so   = ws + 2188800;       // NN*OO*VV      = 819200
    float* qstat  = ws + 3008000;       // 1024 (sum,sumsq per 512 ch); sstat/ostat contiguous after
    float* sstat  = qstat + 1024;       // 48
    float* ostat  = sstat + 48;         // 1024

    void* args[] = {
        (void*)&x, (void*)&w_qkv, (void*)&relative,
        (void*)&bn_qkv_g, (void*)&bn_qkv_b,
        (void*)&bn_sim_g, (void*)&bn_sim_b,
        (void*)&bn_out_g, (void*)&bn_out_b,
        (void*)&w_y, (void*)&w_qkvp, (void*)&w_stk, (void*)&w_so,
        (void*)&qstat, (void*)&sstat, (void*)&ostat,
        (void*)&out
    };
    hipLaunchCooperativeKernel(reinterpret_cast<void*>(k_all),
                               dim3(NBLK), dim3(NTHR), args, 0, stream);
}

// Round 4
// 294.868 us; speedup vs baseline: 1.8703x; 1.8703x over previous
//
#include <hip/hip_runtime.h>
#include <cmath>

#define NN 64
#define CC 256
#define TT 64
#define VV 25
#define OO 512     // 2*out_planes
#define GG 8
#define NV (NN*VV)   // 1600 elements per channel for qkv/so BN
#define STK 625      // V*V

// ---------------- kernel 1: y[n,c,v] = mean_t x[n,c,t,v], 2 rows/block ----------------
// block 0 also zeroes the 2096-float stat accumulator region (same-stream ordering
// guarantees completion before k_gemm's atomics).
__global__ __launch_bounds__(256) void k_mean(const float* __restrict__ x,
                                              float* __restrict__ y,
                                              float* __restrict__ stats) {
    __shared__ float tile[2 * TT * VV];   // 3200 floats = 12.8 KB
    __shared__ float part[2][200];
    int t = threadIdx.x;
    if (blockIdx.x == 0) {
        for (int i = t; i < 2096; i += 256) stats[i] = 0.f;
    }
    const float4* x4 = (const float4*)(x + (size_t)blockIdx.x * 3200);
    float4* t4 = (float4*)tile;
    for (int i = t; i < 800; i += 256) t4[i] = x4[i];
    __syncthreads();
    if (t < 200) {
        int v = t % VV, s = t / VV;       // s in 0..7
        float a0 = 0.f, a1 = 0.f;
        #pragma unroll
        for (int k = 0; k < 8; ++k) {
            a0 += tile[(s * 8 + k) * VV + v];
            a1 += tile[1600 + (s * 8 + k) * VV + v];
        }
        part[0][s * VV + v] = a0;
        part[1][s * VV + v] = a1;
    }
    __syncthreads();
    if (t < 50) {
        int r = t / VV, v = t - VV * (t / VV);
        float a = 0.f;
        #pragma unroll
        for (int s = 0; s < 8; ++s) a += part[r][s * VV + v];
        y[(size_t)blockIdx.x * 50 + r * VV + v] = a * (1.0f / TT);
    }
}

// ---------------- kernel 2: qkv = w @ y, fused per-channel (sum,sumsq) atomics ----------------
__global__ __launch_bounds__(256) void k_gemm(const float* __restrict__ y,
                                              const float* __restrict__ w,
                                              float* __restrict__ qkv,
                                              float* __restrict__ qstat) {
    __shared__ float ys[CC * VV];     // 6400 floats, reused as scratch later
    int n = blockIdx.x >> 3, oc = blockIdx.x & 7;
    int t = threadIdx.x;
    const float* yp = y + (size_t)n * CC * VV;
    for (int i = t; i < CC * VV; i += 256) ys[i] = yp[i];
    __syncthreads();
    int v = t % VV, o0 = t / VV;      // valid for t<200; o0 in 0..7
    int obase = oc * 64 + o0;
    float acc[8] = {0, 0, 0, 0, 0, 0, 0, 0};
    if (t < 200) {
        for (int c = 0; c < CC; c += 4) {
            float y0 = ys[c * VV + v], y1 = ys[(c + 1) * VV + v];
            float y2 = ys[(c + 2) * VV + v], y3 = ys[(c + 3) * VV + v];
            #pragma unroll
            for (int u = 0; u < 8; ++u) {
                const float4 w4 = *(const float4*)&w[(size_t)(obase + u * 8) * CC + c];
                acc[u] += y0 * w4.x + y1 * w4.y + y2 * w4.z + y3 * w4.w;
            }
        }
        #pragma unroll
        for (int u = 0; u < 8; ++u)
            qkv[((size_t)n * OO + obase + u * 8) * VV + v] = acc[u];
    }
    __syncthreads();                  // done reading ys -> reuse as scratch
    if (t < 200) {
        #pragma unroll
        for (int u = 0; u < 8; ++u) ys[(o0 + 8 * u) * VV + v] = acc[u];
    }
    __syncthreads();
    if (t < 64) {
        float s = 0.f, s2 = 0.f;
        #pragma unroll
        for (int k = 0; k < VV; ++k) { float w0 = ys[t * VV + k]; s += w0; s2 += w0 * w0; }
        int ch = oc * 64 + t;
        atomicAdd(&qstat[2 * ch], s);
        atomicAdd(&qstat[2 * ch + 1], s2);
    }
}

// ---------------- kernel 3: qkv-BN -> qk/qr/kr scores, fused sim-stat atomics ----------------
__global__ __launch_bounds__(256) void k_scores(const float* __restrict__ qkv,
                                                const float* __restrict__ rel,
                                                const float* __restrict__ qstat,
                                                const float* __restrict__ gq,
                                                const float* __restrict__ bq,
                                                float* __restrict__ stk,
                                                float* __restrict__ sstat) {
    int n = blockIdx.x >> 3, gidx = blockIdx.x & 7;
    __shared__ float qs[16][VV], ks[16][VV], rs[32][49];
    __shared__ float qscl[32], qshl[32];
    __shared__ float red0[256], red1[256], red2[256];
    int t = threadIdx.x;
    if (t < 32) {
        int o = gidx * 64 + t;
        float s = qstat[2 * o], s2 = qstat[2 * o + 1];
        float m = s * (1.0f / NV), var = s2 * (1.0f / NV) - m * m;
        float sc = gq[o] * rsqrtf(var + 1e-5f);
        qscl[t] = sc; qshl[t] = bq[o] - m * sc;
    }
    __syncthreads();
    for (int i = t; i < 32 * VV; i += 256) {
        int c = i / VV, v = i - c * VV;
        int o = gidx * 64 + c;
        float val = qkv[((size_t)n * OO + o) * VV + v] * qscl[c] + qshl[c];
        if (c < 16) qs[c][v] = val; else ks[c - 16][v] = val;
    }
    for (int i = t; i < 32 * 49; i += 256) rs[i / 49][i % 49] = rel[i];
    __syncthreads();
    float sqk = 0.f, sqr = 0.f, skr = 0.f, sqk2 = 0.f, sqr2 = 0.f, skr2 = 0.f;
    for (int ij = t; ij < STK; ij += 256) {
        int i = ij / VV, j = ij - (ij / VV) * VV;
        float aqk = 0.f, aqr = 0.f, akr = 0.f;
        #pragma unroll
        for (int c = 0; c < 16; ++c) {
            float qv = qs[c][i], kv = ks[c][j];
            aqk += qv * kv;
            aqr += qv * rs[c][i - j + 24];
            akr += kv * rs[16 + c][j - i + 24];
        }
        size_t base = (size_t)n * 24;
        stk[(base + gidx) * STK + ij]      = aqk;
        stk[(base + 8 + gidx) * STK + ij]  = aqr;
        stk[(base + 16 + gidx) * STK + ij] = akr;
        sqk += aqk; sqk2 += aqk * aqk;
        sqr += aqr; sqr2 += aqr * aqr;
        skr += akr; skr2 += akr * akr;
    }
    red0[t] = sqk; red1[t] = sqr; red2[t] = skr;
    __syncthreads();
    for (int off = 128; off > 0; off >>= 1) {
        if (t < off) { red0[t] += red0[t + off]; red1[t] += red1[t + off]; red2[t] += red2[t + off]; }
        __syncthreads();
    }
    if (t == 0) {
        atomicAdd(&sstat[2 * gidx], red0[0]);
        atomicAdd(&sstat[2 * (8 + gidx)], red1[0]);
        atomicAdd(&sstat[2 * (16 + gidx)], red2[0]);
    }
    __syncthreads();
    red0[t] = sqk2; red1[t] = sqr2; red2[t] = skr2;
    __syncthreads();
    for (int off = 128; off > 0; off >>= 1) {
        if (t < off) { red0[t] += red0[t + off]; red1[t] += red1[t + off]; red2[t] += red2[t + off]; }
        __syncthreads();
    }
    if (t == 0) {
        atomicAdd(&sstat[2 * gidx + 1], red0[0]);
        atomicAdd(&sstat[2 * (8 + gidx) + 1], red1[0]);
        atomicAdd(&sstat[2 * (16 + gidx) + 1], red2[0]);
    }
}

// ---------------- kernel 4: sim-BN+sum -> softmax -> sv/sve, fused so-stat atomics ----------------
__global__ __launch_bounds__(256) void k_attnout(const float* __restrict__ stk,
                                                 const float* __restrict__ qkv,
                                                 const float* __restrict__ rel,
                                                 const float* __restrict__ qstat,
                                                 const float* __restrict__ gq,
                                                 const float* __restrict__ bq,
                                                 const float* __restrict__ sstat,
                                                 const float* __restrict__ gs,
                                                 const float* __restrict__ bs,
                                                 float* __restrict__ so,
                                                 float* __restrict__ ostat) {
    int n = blockIdx.x >> 3, gidx = blockIdx.x & 7;
    __shared__ float S[STK];
    __shared__ float vs[32][VV];
    __shared__ float rs[32][49];
    __shared__ float scratch[64 * VV];
    __shared__ float sscl[3], sshl[3], vscl[32], vshl[32];
    int t = threadIdx.x;
    if (t < 3) {
        int ch = 8 * t + gidx;
        float s = sstat[2 * ch], s2 = sstat[2 * ch + 1];
        const float inv = 1.0f / 40000.0f;
        float m = s * inv, var = s2 * inv - m * m;
        float sc = gs[ch] * rsqrtf(var + 1e-5f);
        sscl[t] = sc; sshl[t] = bs[ch] - m * sc;
    }
    if (t >= 32 && t < 64) {
        int c = t - 32;
        int o = gidx * 64 + 32 + c;
        float s = qstat[2 * o], s2 = qstat[2 * o + 1];
        float m = s * (1.0f / NV), var = s2 * (1.0f / NV) - m * m;
        float sc = gq[o] * rsqrtf(var + 1e-5f);
        vscl[c] = sc; vshl[c] = bq[o] - m * sc;
    }
    __syncthreads();
    const size_t sb = (size_t)n * 24 * STK;
    for (int ij = t; ij < STK; ij += 256) {
        float a = stk[sb + (size_t)gidx * STK + ij] * sscl[0] + sshl[0];
        a += stk[sb + (size_t)(8 + gidx) * STK + ij] * sscl[1] + sshl[1];
        a += stk[sb + (size_t)(16 + gidx) * STK + ij] * sscl[2] + sshl[2];
        S[ij] = a;
    }
    for (int i = t; i < 32 * VV; i += 256) {
        int c = i / VV, v = i - (i / VV) * VV;
        int o = gidx * 64 + 32 + c;
        vs[c][v] = qkv[((size_t)n * OO + o) * VV + v] * vscl[c] + vshl[c];
    }
    for (int i = t; i < 32 * 49; i += 256) rs[i / 49][i % 49] = rel[32 * 49 + i];
    __syncthreads();
    if (t < VV) {
        int i = t;
        float m = -1e30f;
        #pragma unroll
        for (int j = 0; j < VV; ++j) m = fmaxf(m, S[i * VV + j]);
        float sum = 0.f;
        float e[VV];
        #pragma unroll
        for (int j = 0; j < VV; ++j) { e[j] = expf(S[i * VV + j] - m); sum += e[j]; }
        float inv = 1.0f / sum;
        #pragma unroll
        for (int j = 0; j < VV; ++j) S[i * VV + j] = e[j] * inv;
    }
    __syncthreads();
    for (int idx = t; idx < 32 * VV; idx += 256) {
        int c = idx / VV, i = idx - (idx / VV) * VV;
        float sv = 0.f, sve = 0.f;
        #pragma unroll
        for (int j = 0; j < VV; ++j) {
            float p = S[i * VV + j];
            sv  += p * vs[c][j];
            sve += p * rs[c][i - j + 24];
        }
        size_t o = (size_t)(gidx * 32 + c) * 2;
        so[((size_t)n * OO + o) * VV + i]     = sv;
        so[((size_t)n * OO + o + 1) * VV + i] = sve;
        scratch[(2 * c) * VV + i]     = sv;
        scratch[(2 * c + 1) * VV + i] = sve;
    }
    __syncthreads();
    if (t < 64) {
        float s = 0.f, s2 = 0.f;
        #pragma unroll
        for (int k = 0; k < VV; ++k) { float w0 = scratch[t * VV + k]; s += w0; s2 += w0 * w0; }
        int ch = gidx * 64 + t;
        atomicAdd(&ostat[2 * ch], s);
        atomicAdd(&ostat[2 * ch + 1], s2);
    }
}

// ---------------- kernel 5: out = x * (1 + sigmoid(bn(so0)+bn(so1))), 2 rows/block ----------------
__global__ __launch_bounds__(256) void k_final(const float* __restrict__ x,
                                               const float* __restrict__ so,
                                               const float* __restrict__ ostat,
                                               const float* __restrict__ go,
                                               const float* __restrict__ bo,
                                               float* __restrict__ out) {
    int t = threadIdx.x;
    __shared__ float orow[2][VV];
    __shared__ float4 g4[2][VV];
    int row0 = blockIdx.x * 2;          // rows row0, row0+1 share n (row0 even)
    int n = row0 >> 8;
    if (t < 50) {
        int r = t / VV, v = t - VV * (t / VV);
        int p = (row0 + r) & 255;
        int ch0 = 2 * p, ch1 = 2 * p + 1;
        float s0 = ostat[2 * ch0], q0 = ostat[2 * ch0 + 1];
        float m0 = s0 * (1.0f / NV), var0 = q0 * (1.0f / NV) - m0 * m0;
        float sc0 = go[ch0] * rsqrtf(var0 + 1e-5f), sh0 = bo[ch0] - m0 * sc0;
        float s1 = ostat[2 * ch1], q1 = ostat[2 * ch1 + 1];
        float m1 = s1 * (1.0f / NV), var1 = q1 * (1.0f / NV) - m1 * m1;
        float sc1 = go[ch1] * rsqrtf(var1 + 1e-5f), sh1 = bo[ch1] - m1 * sc1;
        const float* sop = so + ((size_t)n * OO + ch0) * VV + v;
        float z = (sop[0] * sc0 + sh0) + (sop[VV] * sc1 + sh1);
        orow[r][v] = 1.0f + 1.0f / (1.0f + expf(-z));
    }
    __syncthreads();
    if (t < 50) {                        // gate pattern repeats every 25 float4 (400 % 25 == 0)
        int r = t / VV, j = t - VV * (t / VV);
        int e = 4 * j;
        float4 g;
        g.x = orow[r][e % VV];
        g.y = orow[r][(e + 1) % VV];
        g.z = orow[r][(e + 2) % VV];
        g.w = orow[r][(e + 3) % VV];
        g4[r][j] = g;
    }
    __syncthreads();
    const float4* x4 = (const float4*)(x + (size_t)row0 * (TT * VV));
    float4* o4 = (float4*)(out + (size_t)row0 * (TT * VV));
    int m = t % VV;                      // j = i % 25; 256 % 25 == 6
    for (int i = t; i < 800; i += 256) {
        int r = (i >= 400) ? 1 : 0;
        float4 xv = x4[i];
        float4 g = g4[r][m];
        float4 rr;
        rr.x = xv.x * g.x; rr.y = xv.y * g.y; rr.z = xv.z * g.z; rr.w = xv.w * g.w;
        o4[i] = rr;
        m += 6; if (m >= VV) m -= VV;
    }
}

extern "C" void kernel_launch(void* const* d_in, const int* in_sizes, int n_in,
                              void* d_out, int out_size, void* d_ws, size_t ws_size,
                              hipStream_t stream) {
    (void)in_sizes; (void)n_in; (void)out_size; (void)ws_size;
    const float* x        = (const float*)d_in[0];
    const float* w_qkv    = (const float*)d_in[1];
    const float* relative = (const float*)d_in[2];
    const float* bn_qkv_g = (const float*)d_in[3];
    const float* bn_qkv_b = (const float*)d_in[4];
    const float* bn_sim_g = (const float*)d_in[5];
    const float* bn_sim_b = (const float*)d_in[6];
    const float* bn_out_g = (const float*)d_in[7];
    const float* bn_out_b = (const float*)d_in[8];
    float* out = (float*)d_out;

    float* ws = (float*)d_ws;
    float* w_y    = ws;                 // NN*CC*VV      = 409600
    float* w_qkvp = ws + 409600;        // NN*OO*VV      = 819200
    float* w_stk  = ws + 1228800;       // NN*24*STK     = 960000
    float* w_so   = ws + 2188800;       // NN*OO*VV      = 819200
    float* qstat  = ws + 3008000;       // 1024 (sum,sumsq per 512 ch); sstat/ostat contiguous after
    float* sstat  = qstat + 1024;       // 48
    float* ostat  = sstat + 48;         // 1024

    k_mean<<<NN * CC / 2, 256, 0, stream>>>(x, w_y, qstat);
    k_gemm<<<NN * 8, 256, 0, stream>>>(w_y, w_qkv, w_qkvp, qstat);
    k_scores<<<NN * GG, 256, 0, stream>>>(w_qkvp, relative, qstat, bn_qkv_g, bn_qkv_b, w_stk, sstat);
    k_attnout<<<NN * GG, 256, 0, stream>>>(w_stk, w_qkvp, relative, qstat, bn_qkv_g, bn_qkv_b,
                                           sstat, bn_sim_g, bn_sim_b, w_so, ostat);
    k_final<<<NN * CC / 2, 256, 0, stream>>>(x, w_so, ostat, bn_out_g, bn_out_b, out);
}